// Round 4
// baseline (181.462 us; speedup 1.0000x reference)
//
#include <hip/hip_runtime.h>
#include <hip/hip_bf16.h>

// Problem constants
#define NB 32     // batch
#define NL 2048   // seq len
#define ND 1024   // DQ = DK = NH*DH
#define NHH 16    // heads
#define NDH 64    // head dim

typedef __bf16 bf16;
typedef __attribute__((ext_vector_type(4))) __bf16 bf16x4;
typedef __attribute__((ext_vector_type(8))) __bf16 bf16x8;
typedef __attribute__((ext_vector_type(4))) float f32x4;

__device__ __forceinline__ float dot4(float4 a, float4 b) {
  return a.x * b.x + a.y * b.y + a.z * b.z + a.w * b.w;
}

__device__ __forceinline__ bf16x4 cvt4(f32x4 f) {
  bf16x4 v;
  v[0] = (bf16)f[0]; v[1] = (bf16)f[1]; v[2] = (bf16)f[2]; v[3] = (bf16)f[3];
  return v;
}

// ---------------------------------------------------------------------------
// K1: qs[b][o] = q[b] . Wq[o] + bq[o]      grid=1024, block=256
// ---------------------------------------------------------------------------
__global__ __launch_bounds__(256) void qs_kernel(
    const float* __restrict__ q, const float* __restrict__ Wq,
    const float* __restrict__ bq, float* __restrict__ qs) {
  int o = blockIdx.x;
  int lane = threadIdx.x & 63;
  int wv = threadIdx.x >> 6;
  const float4* wrow = reinterpret_cast<const float4*>(Wq + (size_t)o * ND) + lane * 4;
  float4 w0 = wrow[0], w1 = wrow[1], w2 = wrow[2], w3 = wrow[3];
#pragma unroll
  for (int bb = 0; bb < 8; ++bb) {
    int b = wv * 8 + bb;
    const float4* qr = reinterpret_cast<const float4*>(q + (size_t)b * ND) + lane * 4;
    float s = dot4(qr[0], w0) + dot4(qr[1], w1) + dot4(qr[2], w2) + dot4(qr[3], w3);
#pragma unroll
    for (int off = 32; off > 0; off >>= 1) s += __shfl_down(s, off, 64);
    if (lane == 0) qs[(size_t)b * ND + o] = s + bq[o];
  }
}

// ---------------------------------------------------------------------------
// K2: qt[b][n][i] = sum_d Wk[n*64+d][i] * qs[b][n*64+d]   grid=64
// ---------------------------------------------------------------------------
__global__ __launch_bounds__(256) void qt_kernel(
    const float* __restrict__ Wk, const float* __restrict__ qs,
    float* __restrict__ qt) {
  int n = blockIdx.x >> 2;
  int ic = blockIdx.x & 3;
  int i = ic * 256 + threadIdx.x;
  __shared__ float s_qs[32][64];
  for (int t = threadIdx.x; t < 2048; t += 256) {
    int b = t >> 6, d = t & 63;
    s_qs[b][d] = qs[(size_t)b * ND + n * NDH + d];
  }
  __syncthreads();
  float acc[32];
#pragma unroll
  for (int b = 0; b < 32; ++b) acc[b] = 0.f;
  for (int d = 0; d < 64; ++d) {
    float w = Wk[((size_t)(n * NDH + d)) * ND + i];
#pragma unroll
    for (int b = 0; b < 32; ++b) acc[b] += w * s_qs[b][d];
  }
#pragma unroll
  for (int b = 0; b < 32; ++b)
    qt[((size_t)(b * NHH + n)) * ND + i] = acc[b];
}

// ---------------------------------------------------------------------------
// K2b: qb[b*16+n] = qs[b][n*64+:] . bk[n*64+:]    grid=2, block=256
// ---------------------------------------------------------------------------
__global__ __launch_bounds__(256) void qb_kernel(
    const float* __restrict__ qs, const float* __restrict__ bk,
    float* __restrict__ qb) {
  int t = blockIdx.x * 256 + threadIdx.x;
  if (t >= 512) return;
  int b = t >> 4, n = t & 15;
  float s = 0.f;
  for (int d = 0; d < 64; ++d)
    s += qs[(size_t)b * ND + n * NDH + d] * bk[n * NDH + d];
  qb[t] = s;
}

// ---------------------------------------------------------------------------
// K3 (FUSED): per (b, l-slice of 128): for each 32-l tile:
//   stage k tile f32->bf16 LDS (read k from HBM exactly ONCE)
//   MFMA logits (waves: 2 l-halves x 2 kc-halves, combine via LDS)
//   p = exp(logit)  -> global attn (unnormalized) + LDS sP
//   phase B: ctx partial += p * k  (from same LDS tile)
// ctxp[sl][b][n][i] partial slabs; normalized later.
// grid = 32 b * 16 sl = 512 blocks, 256 threads, LDS 68KB -> 2 blocks/CU.
// ---------------------------------------------------------------------------
__global__ __launch_bounds__(256, 2) void fused_kernel(
    const float* __restrict__ kin, const float* __restrict__ qt,
    const float* __restrict__ qb, float* __restrict__ attn,
    float* __restrict__ ctxp) {
  int bx = blockIdx.x;
  int b  = bx >> 4;
  int sl = bx & 15;
  int tid = threadIdx.x, lane = tid & 63, wv = tid >> 6;
  int lh = wv & 1;   // l-half of this wave's MFMA subtile
  int kh = wv >> 1;  // kc-half

  __shared__ __align__(16) char  kbuf[32 * 1024 * 2];  // 64 KB, XOR-swizzled
  __shared__ __align__(16) float pbuf[32][16];         // partial logits (kh=1)
  __shared__ __align__(16) float sP[32][16];           // exp'd p values

  int n_a = lane & 15;   // A-row (head) this lane loads
  int kg  = lane >> 4;   // k-group

  // A-fragments: qt[b][n][kh*512 + cc*32 + kg*8 + 0..7] as bf16x8, 16 chunks
  bf16x8 afrag[16];
  {
    const float* qrow = qt + ((size_t)(b * NHH + n_a)) * ND + kh * 512 + kg * 8;
#pragma unroll
    for (int cc = 0; cc < 16; ++cc) {
      f32x4 f0 = *reinterpret_cast<const f32x4*>(qrow + cc * 32);
      f32x4 f1 = *reinterpret_cast<const f32x4*>(qrow + cc * 32 + 4);
      bf16x8 v;
      v[0] = (bf16)f0[0]; v[1] = (bf16)f0[1]; v[2] = (bf16)f0[2]; v[3] = (bf16)f0[3];
      v[4] = (bf16)f1[0]; v[5] = (bf16)f1[1]; v[6] = (bf16)f1[2]; v[7] = (bf16)f1[3];
      afrag[cc] = v;
    }
  }
  f32x4 qbv = *reinterpret_cast<const f32x4*>(qb + b * NHH + kg * 4);

  f32x4 ctxacc[16];
#pragma unroll
  for (int n = 0; n < 16; ++n) ctxacc[n] = (f32x4){0.f, 0.f, 0.f, 0.f};

  int i0 = wv * 256 + (lane << 2);  // phase-B column base (4 cols/thread)
  int lB = lh * 16 + (lane & 15);   // MFMA B-col row / p row

  for (int t = 0; t < 4; ++t) {
    int l0 = sl * 128 + t * 32;
    __syncthreads();  // kbuf free (prev tile's phase B done)

    {  // stage k[b][l0..l0+31][0..1023] -> kbuf bf16, swizzled
      int r = tid >> 3, c0 = (tid & 7) * 4;
      const float* src = kin + ((size_t)(b * NL + l0 + r)) * ND + c0;
#pragma unroll
      for (int m = 0; m < 32; ++m) {
        f32x4 f = *reinterpret_cast<const f32x4*>(src + m * 32);
        int byte = (r * 2048 + (c0 + m * 32) * 2) ^ ((r & 7) << 4);
        *reinterpret_cast<bf16x4*>(kbuf + byte) = cvt4(f);
      }
    }
    __syncthreads();

    // phase A: logits for this wave's (l-half, kc-half)
    f32x4 acc = {0.f, 0.f, 0.f, 0.f};
#pragma unroll
    for (int cc = 0; cc < 16; ++cc) {
      int kc = kh * 512 + cc * 32;
      int byteB = ((lB * 1024 + kc + kg * 8) * 2) ^ ((lB & 7) << 4);
      bf16x8 bfr = *reinterpret_cast<const bf16x8*>(kbuf + byteB);
      acc = __builtin_amdgcn_mfma_f32_16x16x32_bf16(afrag[cc], bfr, acc, 0, 0, 0);
    }
    if (kh == 1)
      *reinterpret_cast<f32x4*>(&pbuf[lB][kg * 4]) = acc;
    __syncthreads();
    if (kh == 0) {
      f32x4 other = *reinterpret_cast<const f32x4*>(&pbuf[lB][kg * 4]);
      f32x4 p;
#pragma unroll
      for (int j = 0; j < 4; ++j) {
        float logit = (acc[j] + other[j] + qbv[j]) * 0.125f;
        p[j] = __expf(logit);
        attn[((size_t)((kg * 4 + j) * NB + b)) * NL + l0 + lB] = p[j];
      }
      *reinterpret_cast<f32x4*>(&sP[lB][kg * 4]) = p;
    }
    __syncthreads();

    // phase B: ctxacc[n] += p[l][n] * k[l][i0..i0+3]
#pragma unroll 2
    for (int l = 0; l < 32; ++l) {
      f32x4 p0 = *reinterpret_cast<const f32x4*>(&sP[l][0]);
      f32x4 p1 = *reinterpret_cast<const f32x4*>(&sP[l][4]);
      f32x4 p2 = *reinterpret_cast<const f32x4*>(&sP[l][8]);
      f32x4 p3 = *reinterpret_cast<const f32x4*>(&sP[l][12]);
      int byteK = ((l * 1024 + i0) * 2) ^ ((l & 7) << 4);
      bf16x4 kv = *reinterpret_cast<const bf16x4*>(kbuf + byteK);
      f32x4 kf;
      kf[0] = (float)kv[0]; kf[1] = (float)kv[1];
      kf[2] = (float)kv[2]; kf[3] = (float)kv[3];
#pragma unroll
      for (int n = 0; n < 16; ++n) {
        float pn = (n < 4) ? p0[n] : (n < 8) ? p1[n - 4] : (n < 12) ? p2[n - 8] : p3[n - 12];
        ctxacc[n] += pn * kf;
      }
    }
  }

  // store partial slab
#pragma unroll
  for (int n = 0; n < 16; ++n)
    *reinterpret_cast<f32x4*>(
        ctxp + (((size_t)sl * NB + b) * NHH + n) * ND + i0) = ctxacc[n];
}

// ---------------------------------------------------------------------------
// K4: normalize attn rows (divide by row-sum), write invS. grid=512, block=256
// ---------------------------------------------------------------------------
__global__ __launch_bounds__(256) void norm_kernel(float* __restrict__ attn,
                                                   float* __restrict__ invS) {
  int row = blockIdx.x;
  float* p = attn + (size_t)row * NL;
  int tid = threadIdx.x;
  int lane = tid & 63, wv = tid >> 6;
  float v[8];
  float s = 0.f;
#pragma unroll
  for (int j = 0; j < 8; ++j) {
    v[j] = p[tid + j * 256];
    s += v[j];
  }
#pragma unroll
  for (int off = 32; off > 0; off >>= 1) s += __shfl_down(s, off, 64);
  __shared__ float ss[4];
  if (lane == 0) ss[wv] = s;
  __syncthreads();
  float inv = 1.f / (ss[0] + ss[1] + ss[2] + ss[3]);
  if (tid == 0) invS[row] = inv;
#pragma unroll
  for (int j = 0; j < 8; ++j) p[tid + j * 256] = v[j] * inv;
}

// ---------------------------------------------------------------------------
// K5: ctx = sum_sl ctxp[sl]   (unnormalized). grid=512, block=256, f32x4 each
// ---------------------------------------------------------------------------
__global__ __launch_bounds__(256) void reduce_kernel(
    const float* __restrict__ ctxp, float* __restrict__ ctx) {
  size_t e4 = ((size_t)blockIdx.x * 256 + threadIdx.x) * 4;
  f32x4 s = *reinterpret_cast<const f32x4*>(ctxp + e4);
#pragma unroll
  for (int sl = 1; sl < 16; ++sl)
    s += *reinterpret_cast<const f32x4*>(ctxp + (size_t)sl * NB * NHH * ND + e4);
  *reinterpret_cast<f32x4*>(ctx + e4) = s;
}

// ---------------------------------------------------------------------------
// K6: out[b][o] = (Wv[o].ctx[b][n]) * invS[n*32+b] + bv[o]   grid=1024
// ---------------------------------------------------------------------------
__global__ __launch_bounds__(256) void out_kernel(
    const float* __restrict__ Wv, const float* __restrict__ bv,
    const float* __restrict__ ctx, const float* __restrict__ invS,
    float* __restrict__ out) {
  int o = blockIdx.x;
  int n = o >> 6;
  int lane = threadIdx.x & 63;
  int wv = threadIdx.x >> 6;
  const float4* wrow = reinterpret_cast<const float4*>(Wv + (size_t)o * ND) + lane * 4;
  float4 w0 = wrow[0], w1 = wrow[1], w2 = wrow[2], w3 = wrow[3];
#pragma unroll
  for (int bb = 0; bb < 8; ++bb) {
    int b = wv * 8 + bb;
    const float4* cr =
        reinterpret_cast<const float4*>(ctx + ((size_t)(b * NHH + n)) * ND) + lane * 4;
    float s = dot4(cr[0], w0) + dot4(cr[1], w1) + dot4(cr[2], w2) + dot4(cr[3], w3);
#pragma unroll
    for (int off = 32; off > 0; off >>= 1) s += __shfl_down(s, off, 64);
    if (lane == 0) out[(size_t)b * ND + o] = s * invS[n * NB + b] + bv[o];
  }
}

// ---------------------------------------------------------------------------
extern "C" void kernel_launch(void* const* d_in, const int* in_sizes, int n_in,
                              void* d_out, int out_size, void* d_ws, size_t ws_size,
                              hipStream_t stream) {
  const float* q  = (const float*)d_in[0];
  const float* k  = (const float*)d_in[1];
  const float* Wq = (const float*)d_in[2];
  const float* bq = (const float*)d_in[3];
  const float* Wk = (const float*)d_in[4];
  const float* bk = (const float*)d_in[5];
  const float* Wv = (const float*)d_in[6];
  const float* bv = (const float*)d_in[7];

  float* out  = (float*)d_out;         // [32][1024]
  float* attn = out + NB * ND;         // [512][2048]  (n-major)

  // ws floats: qs 32768 | qt 524288 | qb 512 | invS 512 | ctx 524288 |
  //            ctxp 16*524288
  float* ws   = (float*)d_ws;
  float* qs   = ws;
  float* qt   = qs + 32768;
  float* qb   = qt + 524288;
  float* invS = qb + 512;
  float* ctx  = invS + 512;
  float* ctxp = ctx + 524288;

  qs_kernel<<<1024, 256, 0, stream>>>(q, Wq, bq, qs);
  qt_kernel<<<64, 256, 0, stream>>>(Wk, qs, qt);
  qb_kernel<<<2, 256, 0, stream>>>(qs, bk, qb);
  fused_kernel<<<512, 256, 0, stream>>>(k, qt, qb, attn, ctxp);
  norm_kernel<<<512, 256, 0, stream>>>(attn, invS);
  reduce_kernel<<<512, 256, 0, stream>>>(ctxp, ctx);
  out_kernel<<<1024, 256, 0, stream>>>(Wv, bv, ctx, invS, out);
}

// Round 5
// 172.974 us; speedup vs baseline: 1.0491x; 1.0491x over previous
//
#include <hip/hip_runtime.h>
#include <hip/hip_bf16.h>

// Problem constants
#define NB 32     // batch
#define NL 2048   // seq len
#define ND 1024   // DQ = DK = NH*DH
#define NHH 16    // heads
#define NDH 64    // head dim

typedef __bf16 bf16;
typedef __attribute__((ext_vector_type(4))) __bf16 bf16x4;
typedef __attribute__((ext_vector_type(8))) __bf16 bf16x8;
typedef __attribute__((ext_vector_type(4))) float f32x4;

__device__ __forceinline__ float dot4(float4 a, float4 b) {
  return a.x * b.x + a.y * b.y + a.z * b.z + a.w * b.w;
}

__device__ __forceinline__ bf16x4 cvt4(f32x4 f) {
  bf16x4 v;
  v[0] = (bf16)f[0]; v[1] = (bf16)f[1]; v[2] = (bf16)f[2]; v[3] = (bf16)f[3];
  return v;
}

// ---------------------------------------------------------------------------
// K1: qs[b][o] = q[b] . Wq[o] + bq[o]      grid=1024, block=256
// ---------------------------------------------------------------------------
__global__ __launch_bounds__(256) void qs_kernel(
    const float* __restrict__ q, const float* __restrict__ Wq,
    const float* __restrict__ bq, float* __restrict__ qs) {
  int o = blockIdx.x;
  int lane = threadIdx.x & 63;
  int wv = threadIdx.x >> 6;
  const float4* wrow = reinterpret_cast<const float4*>(Wq + (size_t)o * ND) + lane * 4;
  float4 w0 = wrow[0], w1 = wrow[1], w2 = wrow[2], w3 = wrow[3];
#pragma unroll
  for (int bb = 0; bb < 8; ++bb) {
    int b = wv * 8 + bb;
    const float4* qr = reinterpret_cast<const float4*>(q + (size_t)b * ND) + lane * 4;
    float s = dot4(qr[0], w0) + dot4(qr[1], w1) + dot4(qr[2], w2) + dot4(qr[3], w3);
#pragma unroll
    for (int off = 32; off > 0; off >>= 1) s += __shfl_down(s, off, 64);
    if (lane == 0) qs[(size_t)b * ND + o] = s + bq[o];
  }
}

// ---------------------------------------------------------------------------
// K2: qt[b][n][i] = sum_d Wk[n*64+d][i] * qs[b][n*64+d]   grid=64
// ---------------------------------------------------------------------------
__global__ __launch_bounds__(256) void qt_kernel(
    const float* __restrict__ Wk, const float* __restrict__ qs,
    float* __restrict__ qt) {
  int n = blockIdx.x >> 2;
  int ic = blockIdx.x & 3;
  int i = ic * 256 + threadIdx.x;
  __shared__ float s_qs[32][64];
  for (int t = threadIdx.x; t < 2048; t += 256) {
    int b = t >> 6, d = t & 63;
    s_qs[b][d] = qs[(size_t)b * ND + n * NDH + d];
  }
  __syncthreads();
  float acc[32];
#pragma unroll
  for (int b = 0; b < 32; ++b) acc[b] = 0.f;
  for (int d = 0; d < 64; ++d) {
    float w = Wk[((size_t)(n * NDH + d)) * ND + i];
#pragma unroll
    for (int b = 0; b < 32; ++b) acc[b] += w * s_qs[b][d];
  }
#pragma unroll
  for (int b = 0; b < 32; ++b)
    qt[((size_t)(b * NHH + n)) * ND + i] = acc[b];
}

// ---------------------------------------------------------------------------
// K2b: qb[b*16+n] = qs[b][n*64+:] . bk[n*64+:]    grid=2, block=256
// ---------------------------------------------------------------------------
__global__ __launch_bounds__(256) void qb_kernel(
    const float* __restrict__ qs, const float* __restrict__ bk,
    float* __restrict__ qb) {
  int t = blockIdx.x * 256 + threadIdx.x;
  if (t >= 512) return;
  int b = t >> 4, n = t & 15;
  float s = 0.f;
  for (int d = 0; d < 64; ++d)
    s += qs[(size_t)b * ND + n * NDH + d] * bk[n * NDH + d];
  qb[t] = s;
}

// ---------------------------------------------------------------------------
// K3 (FUSED v2): grid = 32b x 16sl = 512 blocks, 512 threads (8 waves).
// Per block: 8 tiles of 16 l. LDS double-buffered k tile (bf16, XOR-swz).
// Per tile: [issue loads t+1] -> phaseA logits MFMA (8 waves split kc 128 ea)
//   -> stage-write t+1 (other buffer) -> bar -> reduce+exp -> bar
//   -> phaseB ctx MFMA (K=32, upper half zero-padded) -> bar.
// k is read from HBM exactly once.
// ---------------------------------------------------------------------------
__global__ __launch_bounds__(512, 4) void fused_kernel(
    const float* __restrict__ kin, const float* __restrict__ qt,
    const float* __restrict__ qb, float* __restrict__ attn,
    float* __restrict__ ctxp) {
  int bx = blockIdx.x;
  int b  = bx >> 4;
  int sl = bx & 15;
  int tid = threadIdx.x, lane = tid & 63, wv = tid >> 6;
  int kg = lane >> 4;       // 0..3
  int ln16 = lane & 15;

  __shared__ __align__(16) char  kb[2][16 * 1024 * 2];  // 2 x 32 KB
  __shared__ __align__(16) float pbuf[8][16][17];       // [wave][l][n]
  __shared__ __align__(16) float sP[16][17];            // [l][n]

  // afrag: qt[b][n=ln16][wv*128 + mm*32 + kg*8 + 0..7]
  bf16x8 afrag[4];
  {
    const float* qrow = qt + ((size_t)(b * NHH + ln16)) * ND + wv * 128 + kg * 8;
#pragma unroll
    for (int mm = 0; mm < 4; ++mm) {
      f32x4 f0 = *reinterpret_cast<const f32x4*>(qrow + mm * 32);
      f32x4 f1 = *reinterpret_cast<const f32x4*>(qrow + mm * 32 + 4);
      bf16x8 v;
      v[0] = (bf16)f0[0]; v[1] = (bf16)f0[1]; v[2] = (bf16)f0[2]; v[3] = (bf16)f0[3];
      v[4] = (bf16)f1[0]; v[5] = (bf16)f1[1]; v[6] = (bf16)f1[2]; v[7] = (bf16)f1[3];
      afrag[mm] = v;
    }
  }

  // reduce-phase personals (tid<256): value (l = tid&15, n = tid>>4)
  int rn = tid >> 4, rl = tid & 15;
  float qbv = (tid < 256) ? qb[b * NHH + rn] : 0.f;

  f32x4 ctxacc[8];
#pragma unroll
  for (int ch = 0; ch < 8; ++ch) ctxacc[ch] = (f32x4){0.f, 0.f, 0.f, 0.f};

  // stage mapping: row sr = tid>>5 (16 rows), col-vec sc = tid&31
  int sr = tid >> 5, sc = tid & 31;
  const float* ksrc = kin + ((size_t)(b * NL + sl * 128 + sr)) * ND + sc * 4;

  // prologue: stage tile 0 -> kb[0]
  {
    f32x4 ld[8];
#pragma unroll
    for (int m = 0; m < 8; ++m)
      ld[m] = *reinterpret_cast<const f32x4*>(ksrc + m * 128);
#pragma unroll
    for (int m = 0; m < 8; ++m) {
      int byte = (sr * 2048 + sc * 8 + m * 256) ^ ((sr & 7) << 4);
      *reinterpret_cast<bf16x4*>(kb[0] + byte) = cvt4(ld[m]);
    }
  }
  __syncthreads();

  for (int t = 0; t < 8; ++t) {
    int bb = t & 1;

    // 1. issue next tile's global loads (registers); write later
    f32x4 ld[8];
    if (t < 7) {
      const float* src = ksrc + (size_t)(t + 1) * 16 * ND;
#pragma unroll
      for (int m = 0; m < 8; ++m)
        ld[m] = *reinterpret_cast<const f32x4*>(src + m * 128);
    }

    // 2. phase A: partial logits, this wave covers kc = wv*128 .. +127
    f32x4 acc = {0.f, 0.f, 0.f, 0.f};
#pragma unroll
    for (int mm = 0; mm < 4; ++mm) {
      int kc = wv * 128 + mm * 32 + kg * 8;
      int byteB = (ln16 * 2048 + kc * 2) ^ ((ln16 & 7) << 4);
      bf16x8 bfr = *reinterpret_cast<const bf16x8*>(kb[bb] + byteB);
      acc = __builtin_amdgcn_mfma_f32_16x16x32_bf16(afrag[mm], bfr, acc, 0, 0, 0);
    }
    {
      int rb = kg * 4;
#pragma unroll
      for (int j = 0; j < 4; ++j) pbuf[wv][ln16][rb + j] = acc[j];
    }

    // 3. stage-write next tile into the other buffer
    if (t < 7) {
#pragma unroll
      for (int m = 0; m < 8; ++m) {
        int byte = (sr * 2048 + sc * 8 + m * 256) ^ ((sr & 7) << 4);
        *reinterpret_cast<bf16x4*>(kb[bb ^ 1] + byte) = cvt4(ld[m]);
      }
    }
    __syncthreads();

    // 4. reduce partials + exp -> sP, attn (unnormalized)
    if (tid < 256) {
      float s = 0.f;
#pragma unroll
      for (int w = 0; w < 8; ++w) s += pbuf[w][rl][rn];
      float p = __expf((s + qbv) * 0.125f);
      sP[rl][rn] = p;
      attn[((size_t)(rn * NB + b)) * NL + sl * 128 + t * 16 + rl] = p;
    }
    __syncthreads();

    // 5. phase B: ctx += p^T-weighted k rows, via MFMA K=32 (upper half zero)
    bf16x8 pa;
    if (kg < 2) {
#pragma unroll
      for (int jj = 0; jj < 8; ++jj) pa[jj] = (bf16)sP[kg * 8 + jj][ln16];
    } else {
#pragma unroll
      for (int jj = 0; jj < 8; ++jj) pa[jj] = (bf16)0.f;
    }
#pragma unroll
    for (int ch = 0; ch < 8; ++ch) {
      int icol = wv * 128 + ch * 16 + ln16;
      bf16x8 pb;
#pragma unroll
      for (int jj = 0; jj < 8; ++jj) {
        int lp = (kg & 1) * 8 + jj;  // in-bounds remap for kg>=2 (pa==0 there)
        int byte = (lp * 2048 + icol * 2) ^ ((lp & 7) << 4);
        pb[jj] = *reinterpret_cast<const bf16*>(kb[bb] + byte);
      }
      ctxacc[ch] = __builtin_amdgcn_mfma_f32_16x16x32_bf16(pa, pb, ctxacc[ch], 0, 0, 0);
    }
    __syncthreads();
  }

  // epilogue: ctx partial slab for this sl
  {
    int rb = kg * 4;
#pragma unroll
    for (int ch = 0; ch < 8; ++ch) {
      int icol = wv * 128 + ch * 16 + ln16;
#pragma unroll
      for (int j = 0; j < 4; ++j) {
        int n = rb + j;
        ctxp[(((size_t)sl * NB + b) * NHH + n) * ND + icol] = ctxacc[ch][j];
      }
    }
  }
}

// ---------------------------------------------------------------------------
// K4: normalize attn rows (divide by row-sum), write invS. grid=512, block=256
// ---------------------------------------------------------------------------
__global__ __launch_bounds__(256) void norm_kernel(float* __restrict__ attn,
                                                   float* __restrict__ invS) {
  int row = blockIdx.x;
  float* p = attn + (size_t)row * NL;
  int tid = threadIdx.x;
  int lane = tid & 63, wv = tid >> 6;
  float v[8];
  float s = 0.f;
#pragma unroll
  for (int j = 0; j < 8; ++j) {
    v[j] = p[tid + j * 256];
    s += v[j];
  }
#pragma unroll
  for (int off = 32; off > 0; off >>= 1) s += __shfl_down(s, off, 64);
  __shared__ float ss[4];
  if (lane == 0) ss[wv] = s;
  __syncthreads();
  float inv = 1.f / (ss[0] + ss[1] + ss[2] + ss[3]);
  if (tid == 0) invS[row] = inv;
#pragma unroll
  for (int j = 0; j < 8; ++j) p[tid + j * 256] = v[j] * inv;
}

// ---------------------------------------------------------------------------
// K5: ctx = sum_sl ctxp[sl]  (unnormalized). grid=512, block=256, f32x4 each
// ---------------------------------------------------------------------------
__global__ __launch_bounds__(256) void reduce_kernel(
    const float* __restrict__ ctxp, float* __restrict__ ctx) {
  size_t e4 = ((size_t)blockIdx.x * 256 + threadIdx.x) * 4;
  f32x4 s = *reinterpret_cast<const f32x4*>(ctxp + e4);
#pragma unroll
  for (int sl = 1; sl < 16; ++sl)
    s += *reinterpret_cast<const f32x4*>(ctxp + (size_t)sl * NB * NHH * ND + e4);
  *reinterpret_cast<f32x4*>(ctx + e4) = s;
}

// ---------------------------------------------------------------------------
// K6: out[b][o] = (Wv[o].ctx[b][n]) * invS[n*32+b] + bv[o]   grid=1024
// ---------------------------------------------------------------------------
__global__ __launch_bounds__(256) void out_kernel(
    const float* __restrict__ Wv, const float* __restrict__ bv,
    const float* __restrict__ ctx, const float* __restrict__ invS,
    float* __restrict__ out) {
  int o = blockIdx.x;
  int n = o >> 6;
  int lane = threadIdx.x & 63;
  int wv = threadIdx.x >> 6;
  const float4* wrow = reinterpret_cast<const float4*>(Wv + (size_t)o * ND) + lane * 4;
  float4 w0 = wrow[0], w1 = wrow[1], w2 = wrow[2], w3 = wrow[3];
#pragma unroll
  for (int bb = 0; bb < 8; ++bb) {
    int b = wv * 8 + bb;
    const float4* cr =
        reinterpret_cast<const float4*>(ctx + ((size_t)(b * NHH + n)) * ND) + lane * 4;
    float s = dot4(cr[0], w0) + dot4(cr[1], w1) + dot4(cr[2], w2) + dot4(cr[3], w3);
#pragma unroll
    for (int off = 32; off > 0; off >>= 1) s += __shfl_down(s, off, 64);
    if (lane == 0) out[(size_t)b * ND + o] = s * invS[n * NB + b] + bv[o];
  }
}

// ---------------------------------------------------------------------------
extern "C" void kernel_launch(void* const* d_in, const int* in_sizes, int n_in,
                              void* d_out, int out_size, void* d_ws, size_t ws_size,
                              hipStream_t stream) {
  const float* q  = (const float*)d_in[0];
  const float* k  = (const float*)d_in[1];
  const float* Wq = (const float*)d_in[2];
  const float* bq = (const float*)d_in[3];
  const float* Wk = (const float*)d_in[4];
  const float* bk = (const float*)d_in[5];
  const float* Wv = (const float*)d_in[6];
  const float* bv = (const float*)d_in[7];

  float* out  = (float*)d_out;         // [32][1024]
  float* attn = out + NB * ND;         // [512][2048]  (n-major)

  // ws floats: qs 32768 | qt 524288 | qb 512 | invS 512 | ctx 524288 |
  //            ctxp 16*524288
  float* ws   = (float*)d_ws;
  float* qs   = ws;
  float* qt   = qs + 32768;
  float* qb   = qt + 524288;
  float* invS = qb + 512;
  float* ctx  = invS + 512;
  float* ctxp = ctx + 524288;

  qs_kernel<<<1024, 256, 0, stream>>>(q, Wq, bq, qs);
  qt_kernel<<<64, 256, 0, stream>>>(Wk, qs, qt);
  qb_kernel<<<2, 256, 0, stream>>>(qs, bk, qb);
  fused_kernel<<<512, 512, 0, stream>>>(k, qt, qb, attn, ctxp);
  norm_kernel<<<512, 256, 0, stream>>>(attn, invS);
  reduce_kernel<<<512, 256, 0, stream>>>(ctxp, ctx);
  out_kernel<<<1024, 256, 0, stream>>>(Wv, bv, ctx, invS, out);
}

// Round 6
// 134.179 us; speedup vs baseline: 1.3524x; 1.2891x over previous
//
#include <hip/hip_runtime.h>
#include <hip/hip_bf16.h>

// Problem constants
#define NB 32     // batch
#define NL 2048   // seq len
#define ND 1024   // DQ = DK = NH*DH
#define NHH 16    // heads
#define NDH 64    // head dim

// LDS row swizzle: rows r and r+8 get disjoint bank sets (bit5 via (r&8)<<2),
// rows within 0..7 spread by (r&7)<<4. XOR applied to byte offset in row.
#define SWZ(r) ((((r) & 7) << 4) ^ (((r) & 8) << 2))

typedef __bf16 bf16;
typedef __attribute__((ext_vector_type(4))) __bf16 bf16x4;
typedef __attribute__((ext_vector_type(8))) __bf16 bf16x8;
typedef __attribute__((ext_vector_type(4))) float f32x4;

__device__ __forceinline__ float dot4(float4 a, float4 b) {
  return a.x * b.x + a.y * b.y + a.z * b.z + a.w * b.w;
}

__device__ __forceinline__ bf16x4 cvt4(f32x4 f) {
  bf16x4 v;
  v[0] = (bf16)f[0]; v[1] = (bf16)f[1]; v[2] = (bf16)f[2]; v[3] = (bf16)f[3];
  return v;
}

// ---------------------------------------------------------------------------
// K1: qs[b][o] = q[b] . Wq[o] + bq[o]      grid=1024, block=256
// ---------------------------------------------------------------------------
__global__ __launch_bounds__(256) void qs_kernel(
    const float* __restrict__ q, const float* __restrict__ Wq,
    const float* __restrict__ bq, float* __restrict__ qs) {
  int o = blockIdx.x;
  int lane = threadIdx.x & 63;
  int wv = threadIdx.x >> 6;
  const float4* wrow = reinterpret_cast<const float4*>(Wq + (size_t)o * ND) + lane * 4;
  float4 w0 = wrow[0], w1 = wrow[1], w2 = wrow[2], w3 = wrow[3];
#pragma unroll
  for (int bb = 0; bb < 8; ++bb) {
    int b = wv * 8 + bb;
    const float4* qr = reinterpret_cast<const float4*>(q + (size_t)b * ND) + lane * 4;
    float s = dot4(qr[0], w0) + dot4(qr[1], w1) + dot4(qr[2], w2) + dot4(qr[3], w3);
#pragma unroll
    for (int off = 32; off > 0; off >>= 1) s += __shfl_down(s, off, 64);
    if (lane == 0) qs[(size_t)b * ND + o] = s + bq[o];
  }
}

// ---------------------------------------------------------------------------
// K2: qt[b][n][i] = sum_d Wk[n*64+d][i] * qs[b][n*64+d]   grid=64
// ---------------------------------------------------------------------------
__global__ __launch_bounds__(256) void qt_kernel(
    const float* __restrict__ Wk, const float* __restrict__ qs,
    float* __restrict__ qt) {
  int n = blockIdx.x >> 2;
  int ic = blockIdx.x & 3;
  int i = ic * 256 + threadIdx.x;
  __shared__ float s_qs[32][64];
  for (int t = threadIdx.x; t < 2048; t += 256) {
    int b = t >> 6, d = t & 63;
    s_qs[b][d] = qs[(size_t)b * ND + n * NDH + d];
  }
  __syncthreads();
  float acc[32];
#pragma unroll
  for (int b = 0; b < 32; ++b) acc[b] = 0.f;
  for (int d = 0; d < 64; ++d) {
    float w = Wk[((size_t)(n * NDH + d)) * ND + i];
#pragma unroll
    for (int b = 0; b < 32; ++b) acc[b] += w * s_qs[b][d];
  }
#pragma unroll
  for (int b = 0; b < 32; ++b)
    qt[((size_t)(b * NHH + n)) * ND + i] = acc[b];
}

// ---------------------------------------------------------------------------
// K2b: qb[b*16+n] = qs[b][n*64+:] . bk[n*64+:]    grid=2, block=256
// ---------------------------------------------------------------------------
__global__ __launch_bounds__(256) void qb_kernel(
    const float* __restrict__ qs, const float* __restrict__ bk,
    float* __restrict__ qb) {
  int t = blockIdx.x * 256 + threadIdx.x;
  if (t >= 512) return;
  int b = t >> 4, n = t & 15;
  float s = 0.f;
  for (int d = 0; d < 64; ++d)
    s += qs[(size_t)b * ND + n * NDH + d] * bk[n * NDH + d];
  qb[t] = s;
}

// ---------------------------------------------------------------------------
// K3 (FUSED v3): grid = 32b x 16sl = 512 blocks, 512 threads (8 waves).
// Per block: 8 tiles of 16 l. LDS double-buffered bf16 k tile, SWZ-swizzled.
// Changes vs v2: no register prefetch (VGPR<=128, no spill); stronger swizzle
// (rows jj / jj+8 on disjoint banks -> phase-B gather ~conflict-free).
// k is read from HBM exactly once.
// ---------------------------------------------------------------------------
__global__ __launch_bounds__(512, 4) void fused_kernel(
    const float* __restrict__ kin, const float* __restrict__ qt,
    const float* __restrict__ qb, float* __restrict__ attn,
    float* __restrict__ ctxp) {
  int bx = blockIdx.x;
  int b  = bx >> 4;
  int sl = bx & 15;
  int tid = threadIdx.x, lane = tid & 63, wv = tid >> 6;
  int kg = lane >> 4;       // 0..3
  int ln16 = lane & 15;

  __shared__ __align__(16) char  kb[2][16 * 1024 * 2];  // 2 x 32 KB
  __shared__ __align__(16) float pbuf[8][16][17];       // [wave][l][n]
  __shared__ __align__(16) float sP[16][17];            // [l][n]

  // afrag: qt[b][n=ln16][wv*128 + mm*32 + kg*8 + 0..7]
  bf16x8 afrag[4];
  {
    const float* qrow = qt + ((size_t)(b * NHH + ln16)) * ND + wv * 128 + kg * 8;
#pragma unroll
    for (int mm = 0; mm < 4; ++mm) {
      f32x4 f0 = *reinterpret_cast<const f32x4*>(qrow + mm * 32);
      f32x4 f1 = *reinterpret_cast<const f32x4*>(qrow + mm * 32 + 4);
      bf16x8 v;
      v[0] = (bf16)f0[0]; v[1] = (bf16)f0[1]; v[2] = (bf16)f0[2]; v[3] = (bf16)f0[3];
      v[4] = (bf16)f1[0]; v[5] = (bf16)f1[1]; v[6] = (bf16)f1[2]; v[7] = (bf16)f1[3];
      afrag[mm] = v;
    }
  }

  // reduce-phase personals (tid<256): output (l = tid&15, n = tid>>4)
  int rn = tid >> 4, rl = tid & 15;
  float qbv = (tid < 256) ? qb[b * NHH + rn] : 0.f;

  f32x4 ctxacc[8];
#pragma unroll
  for (int ch = 0; ch < 8; ++ch) ctxacc[ch] = (f32x4){0.f, 0.f, 0.f, 0.f};

  // stage mapping: row sr = tid>>5 (16 rows), col-group sc = tid&31
  int sr = tid >> 5, sc = tid & 31;
  const float* ksrc = kin + ((size_t)(b * NL + sl * 128 + sr)) * ND + sc * 4;

  // prologue: stage tile 0 -> kb[0]
#pragma unroll
  for (int m = 0; m < 8; ++m) {
    f32x4 f = *reinterpret_cast<const f32x4*>(ksrc + m * 128);
    int byte = (sr * 2048 + ((sc * 8 + m * 256) ^ SWZ(sr)));
    *reinterpret_cast<bf16x4*>(kb[0] + byte) = cvt4(f);
  }
  __syncthreads();

  for (int t = 0; t < 8; ++t) {
    int bb = t & 1;

    // phase A: partial logits, this wave covers kc = wv*128 .. +127
    f32x4 acc = {0.f, 0.f, 0.f, 0.f};
#pragma unroll
    for (int mm = 0; mm < 4; ++mm) {
      int kc = wv * 128 + mm * 32 + kg * 8;
      int byteB = (ln16 * 2048 + ((kc * 2) ^ SWZ(ln16)));
      bf16x8 bfr = *reinterpret_cast<const bf16x8*>(kb[bb] + byteB);
      acc = __builtin_amdgcn_mfma_f32_16x16x32_bf16(afrag[mm], bfr, acc, 0, 0, 0);
    }
    {
      int rb = kg * 4;
#pragma unroll
      for (int j = 0; j < 4; ++j) pbuf[wv][ln16][rb + j] = acc[j];
    }

    // stage next tile into the other buffer (load -> cvt -> ds_write)
    if (t < 7) {
      const float* src = ksrc + (size_t)(t + 1) * 16 * ND;
#pragma unroll
      for (int m = 0; m < 8; ++m) {
        f32x4 f = *reinterpret_cast<const f32x4*>(src + m * 128);
        int byte = (sr * 2048 + ((sc * 8 + m * 256) ^ SWZ(sr)));
        *reinterpret_cast<bf16x4*>(kb[bb ^ 1] + byte) = cvt4(f);
      }
    }
    __syncthreads();

    // reduce partials + exp -> sP, attn (unnormalized)
    if (tid < 256) {
      float s = 0.f;
#pragma unroll
      for (int w = 0; w < 8; ++w) s += pbuf[w][rl][rn];
      float p = __expf((s + qbv) * 0.125f);
      sP[rl][rn] = p;
      attn[((size_t)(rn * NB + b)) * NL + sl * 128 + t * 16 + rl] = p;
    }
    __syncthreads();

    // phase B: ctx += p-weighted k rows via MFMA K=32 (upper K-half zero).
    // kg>=2 lanes duplicate kg-2 addresses (values x 0) -> LDS broadcast.
    bf16x8 pa;
    if (kg < 2) {
#pragma unroll
      for (int jj = 0; jj < 8; ++jj) pa[jj] = (bf16)sP[kg * 8 + jj][ln16];
    } else {
#pragma unroll
      for (int jj = 0; jj < 8; ++jj) pa[jj] = (bf16)0.f;
    }
#pragma unroll
    for (int ch = 0; ch < 8; ++ch) {
      int icol = wv * 128 + ch * 16 + ln16;
      bf16x8 pb;
#pragma unroll
      for (int jj = 0; jj < 8; ++jj) {
        int lp = (kg & 1) * 8 + jj;
        int byte = (lp * 2048 + ((icol * 2) ^ SWZ(lp)));
        pb[jj] = *reinterpret_cast<const bf16*>(kb[bb] + byte);
      }
      ctxacc[ch] = __builtin_amdgcn_mfma_f32_16x16x32_bf16(pa, pb, ctxacc[ch], 0, 0, 0);
    }
    __syncthreads();
  }

  // epilogue: ctx partial slab for this sl
  {
    int rb = kg * 4;
#pragma unroll
    for (int ch = 0; ch < 8; ++ch) {
      int icol = wv * 128 + ch * 16 + ln16;
#pragma unroll
      for (int j = 0; j < 4; ++j) {
        int n = rb + j;
        ctxp[(((size_t)sl * NB + b) * NHH + n) * ND + icol] = ctxacc[ch][j];
      }
    }
  }
}

// ---------------------------------------------------------------------------
// K4: normalize attn rows (divide by row-sum), write invS. grid=512, block=256
// ---------------------------------------------------------------------------
__global__ __launch_bounds__(256) void norm_kernel(float* __restrict__ attn,
                                                   float* __restrict__ invS) {
  int row = blockIdx.x;
  float* p = attn + (size_t)row * NL;
  int tid = threadIdx.x;
  int lane = tid & 63, wv = tid >> 6;
  float v[8];
  float s = 0.f;
#pragma unroll
  for (int j = 0; j < 8; ++j) {
    v[j] = p[tid + j * 256];
    s += v[j];
  }
#pragma unroll
  for (int off = 32; off > 0; off >>= 1) s += __shfl_down(s, off, 64);
  __shared__ float ss[4];
  if (lane == 0) ss[wv] = s;
  __syncthreads();
  float inv = 1.f / (ss[0] + ss[1] + ss[2] + ss[3]);
  if (tid == 0) invS[row] = inv;
#pragma unroll
  for (int j = 0; j < 8; ++j) p[tid + j * 256] = v[j] * inv;
}

// ---------------------------------------------------------------------------
// K5: ctx = sum_sl ctxp[sl]  (unnormalized). grid=512, block=256, f32x4 each
// ---------------------------------------------------------------------------
__global__ __launch_bounds__(256) void reduce_kernel(
    const float* __restrict__ ctxp, float* __restrict__ ctx) {
  size_t e4 = ((size_t)blockIdx.x * 256 + threadIdx.x) * 4;
  f32x4 s = *reinterpret_cast<const f32x4*>(ctxp + e4);
#pragma unroll
  for (int sl = 1; sl < 16; ++sl)
    s += *reinterpret_cast<const f32x4*>(ctxp + (size_t)sl * NB * NHH * ND + e4);
  *reinterpret_cast<f32x4*>(ctx + e4) = s;
}

// ---------------------------------------------------------------------------
// K6: out[b][o] = (Wv[o].ctx[b][n]) * invS[n*32+b] + bv[o]   grid=1024
// ---------------------------------------------------------------------------
__global__ __launch_bounds__(256) void out_kernel(
    const float* __restrict__ Wv, const float* __restrict__ bv,
    const float* __restrict__ ctx, const float* __restrict__ invS,
    float* __restrict__ out) {
  int o = blockIdx.x;
  int n = o >> 6;
  int lane = threadIdx.x & 63;
  int wv = threadIdx.x >> 6;
  const float4* wrow = reinterpret_cast<const float4*>(Wv + (size_t)o * ND) + lane * 4;
  float4 w0 = wrow[0], w1 = wrow[1], w2 = wrow[2], w3 = wrow[3];
#pragma unroll
  for (int bb = 0; bb < 8; ++bb) {
    int b = wv * 8 + bb;
    const float4* cr =
        reinterpret_cast<const float4*>(ctx + ((size_t)(b * NHH + n)) * ND) + lane * 4;
    float s = dot4(cr[0], w0) + dot4(cr[1], w1) + dot4(cr[2], w2) + dot4(cr[3], w3);
#pragma unroll
    for (int off = 32; off > 0; off >>= 1) s += __shfl_down(s, off, 64);
    if (lane == 0) out[(size_t)b * ND + o] = s * invS[n * NB + b] + bv[o];
  }
}

// ---------------------------------------------------------------------------
extern "C" void kernel_launch(void* const* d_in, const int* in_sizes, int n_in,
                              void* d_out, int out_size, void* d_ws, size_t ws_size,
                              hipStream_t stream) {
  const float* q  = (const float*)d_in[0];
  const float* k  = (const float*)d_in[1];
  const float* Wq = (const float*)d_in[2];
  const float* bq = (const float*)d_in[3];
  const float* Wk = (const float*)d_in[4];
  const float* bk = (const float*)d_in[5];
  const float* Wv = (const float*)d_in[6];
  const float* bv = (const float*)d_in[7];

  float* out  = (float*)d_out;         // [32][1024]
  float* attn = out + NB * ND;         // [512][2048]  (n-major)

  // ws floats: qs 32768 | qt 524288 | qb 512 | invS 512 | ctx 524288 |
  //            ctxp 16*524288
  float* ws   = (float*)d_ws;
  float* qs   = ws;
  float* qt   = qs + 32768;
  float* qb   = qt + 524288;
  float* invS = qb + 512;
  float* ctx  = invS + 512;
  float* ctxp = ctx + 524288;

  qs_kernel<<<1024, 256, 0, stream>>>(q, Wq, bq, qs);
  qt_kernel<<<64, 256, 0, stream>>>(Wk, qs, qt);
  qb_kernel<<<2, 256, 0, stream>>>(qs, bk, qb);
  fused_kernel<<<512, 512, 0, stream>>>(k, qt, qb, attn, ctxp);
  norm_kernel<<<512, 256, 0, stream>>>(attn, invS);
  reduce_kernel<<<512, 256, 0, stream>>>(ctxp, ctx);
  out_kernel<<<1024, 256, 0, stream>>>(Wv, bv, ctx, invS, out);
}

// Round 7
// 133.810 us; speedup vs baseline: 1.3561x; 1.0028x over previous
//
#include <hip/hip_runtime.h>
#include <hip/hip_bf16.h>

// Problem constants
#define NB 32     // batch
#define NL 2048   // seq len
#define ND 1024   // DQ = DK = NH*DH
#define NHH 16    // heads
#define NDH 64    // head dim

typedef __bf16 bf16;
typedef __attribute__((ext_vector_type(4))) __bf16 bf16x4;
typedef __attribute__((ext_vector_type(8))) __bf16 bf16x8;
typedef __attribute__((ext_vector_type(4))) float f32x4;

#define SBAR __builtin_amdgcn_s_barrier()
#define WAIT_LGKM0 asm volatile("s_waitcnt lgkmcnt(0)" ::: "memory")

// k-row swizzle on 16B granules (both-sides involution, rule #21)
#define KSWZ(l) (((l) & 7) << 4)

__device__ __forceinline__ float dot4(float4 a, float4 b) {
  return a.x * b.x + a.y * b.y + a.z * b.z + a.w * b.w;
}

// ---------------------------------------------------------------------------
// K1: qs[b][o] = q[b] . Wq[o] + bq[o]      grid=1024, block=256
// ---------------------------------------------------------------------------
__global__ __launch_bounds__(256) void qs_kernel(
    const float* __restrict__ q, const float* __restrict__ Wq,
    const float* __restrict__ bq, float* __restrict__ qs) {
  int o = blockIdx.x;
  int lane = threadIdx.x & 63;
  int wv = threadIdx.x >> 6;
  const float4* wrow = reinterpret_cast<const float4*>(Wq + (size_t)o * ND) + lane * 4;
  float4 w0 = wrow[0], w1 = wrow[1], w2 = wrow[2], w3 = wrow[3];
#pragma unroll
  for (int bb = 0; bb < 8; ++bb) {
    int b = wv * 8 + bb;
    const float4* qr = reinterpret_cast<const float4*>(q + (size_t)b * ND) + lane * 4;
    float s = dot4(qr[0], w0) + dot4(qr[1], w1) + dot4(qr[2], w2) + dot4(qr[3], w3);
#pragma unroll
    for (int off = 32; off > 0; off >>= 1) s += __shfl_down(s, off, 64);
    if (lane == 0) qs[(size_t)b * ND + o] = s + bq[o];
  }
}

// ---------------------------------------------------------------------------
// K2: qt[b][n][i] = sum_d Wk[n*64+d][i] * qs[b][n*64+d]   grid=64
// ---------------------------------------------------------------------------
__global__ __launch_bounds__(256) void qt_kernel(
    const float* __restrict__ Wk, const float* __restrict__ qs,
    float* __restrict__ qt) {
  int n = blockIdx.x >> 2;
  int ic = blockIdx.x & 3;
  int i = ic * 256 + threadIdx.x;
  __shared__ float s_qs[32][64];
  for (int t = threadIdx.x; t < 2048; t += 256) {
    int b = t >> 6, d = t & 63;
    s_qs[b][d] = qs[(size_t)b * ND + n * NDH + d];
  }
  __syncthreads();
  float acc[32];
#pragma unroll
  for (int b = 0; b < 32; ++b) acc[b] = 0.f;
  for (int d = 0; d < 64; ++d) {
    float w = Wk[((size_t)(n * NDH + d)) * ND + i];
#pragma unroll
    for (int b = 0; b < 32; ++b) acc[b] += w * s_qs[b][d];
  }
#pragma unroll
  for (int b = 0; b < 32; ++b)
    qt[((size_t)(b * NHH + n)) * ND + i] = acc[b];
}

// ---------------------------------------------------------------------------
// K2b: qb[b*16+n] = qs[b][n*64+:] . bk[n*64+:]    grid=2, block=256
// ---------------------------------------------------------------------------
__global__ __launch_bounds__(256) void qb_kernel(
    const float* __restrict__ qs, const float* __restrict__ bk,
    float* __restrict__ qb) {
  int t = blockIdx.x * 256 + threadIdx.x;
  if (t >= 512) return;
  int b = t >> 4, n = t & 15;
  float s = 0.f;
  for (int d = 0; d < 64; ++d)
    s += qs[(size_t)b * ND + n * NDH + d] * bk[n * NDH + d];
  qb[t] = s;
}

// ---------------------------------------------------------------------------
// K3 (FUSED v4): grid = 32b x 16sl = 512 blocks, 512 threads (8 waves).
// k stored f32 in LDS (2 x 64KB dbuf, KSWZ 16B-granule swizzle). T14 split:
// tile t+1 global loads issued at tile-t start, ds_write after phase B.
// Raw s_barrier + explicit lgkmcnt (no vmcnt drain at barriers).
// Phase A: bf16 MFMA logits (cvt at read). Phase B: per-thread (lh,ic)
// f32 VALU FMA from conflict-free b128 reads. k read from HBM exactly once.
// ---------------------------------------------------------------------------
__global__ __launch_bounds__(512, 2) void fused_kernel(
    const float* __restrict__ kin, const float* __restrict__ qt,
    const float* __restrict__ qb, float* __restrict__ attn,
    float* __restrict__ ctxp) {
  int bx = blockIdx.x;
  int b  = bx >> 4;
  int sl = bx & 15;
  int tid = threadIdx.x, lane = tid & 63, wv = tid >> 6;
  int kg = lane >> 4;       // 0..3
  int ln16 = lane & 15;

  __shared__ __align__(16) char  kb[2][16 * 1024 * 4];  // 2 x 64 KB (f32)
  __shared__ __align__(16) float pbuf[8][16][20];       // [wave][l][n] padded
  __shared__ __align__(16) float sP[16][20];            // [l][n] padded

  // afrag: qt[b][n=ln16][wv*128 + mm*32 + kg*8 + 0..7]  (bf16)
  bf16x8 afrag[4];
  {
    const float* qrow = qt + ((size_t)(b * NHH + ln16)) * ND + wv * 128 + kg * 8;
#pragma unroll
    for (int mm = 0; mm < 4; ++mm) {
      f32x4 f0 = *reinterpret_cast<const f32x4*>(qrow + mm * 32);
      f32x4 f1 = *reinterpret_cast<const f32x4*>(qrow + mm * 32 + 4);
      bf16x8 v;
      v[0] = (bf16)f0[0]; v[1] = (bf16)f0[1]; v[2] = (bf16)f0[2]; v[3] = (bf16)f0[3];
      v[4] = (bf16)f1[0]; v[5] = (bf16)f1[1]; v[6] = (bf16)f1[2]; v[7] = (bf16)f1[3];
      afrag[mm] = v;
    }
  }

  // reduce-phase personals (tid<256): (l = tid&15, n = tid>>4)
  int rn = tid >> 4, rl = tid & 15;
  float qbv = (tid < 256) ? qb[b * NHH + rn] : 0.f;

  // phase-B personals: thread covers i = ic*4..+3, l = lh*8..+7
  int ic = tid & 255, lh = tid >> 8;
  f32x4 ctxa[16];
#pragma unroll
  for (int n = 0; n < 16; ++n) ctxa[n] = (f32x4){0.f, 0.f, 0.f, 0.f};

  // stage addressing: chunk = wv*8+m covers LDS [chunk*1024 .. +1023]
  // row l = chunk>>2, in-row byte c4 = (chunk&3)*1024 + lane*16, global
  // source byte = c4 ^ KSWZ(l)  (pre-swizzled source, linear-ish LDS).
  const char* kbase = (const char*)(kin + ((size_t)(b * NL + sl * 128)) * ND);

  // prologue: load+write tile 0 -> kb[0]
  {
#pragma unroll
    for (int m = 0; m < 8; ++m) {
      int chunk = wv * 8 + m;
      int l = chunk >> 2;
      int c4 = (chunk & 3) * 1024 + lane * 16;
      f32x4 v = *reinterpret_cast<const f32x4*>(
          kbase + (size_t)l * 4096 + (c4 ^ KSWZ(l)));
      *reinterpret_cast<f32x4*>(kb[0] + chunk * 1024 + lane * 16) = v;
    }
  }
  WAIT_LGKM0;
  SBAR;

  for (int t = 0; t < 8; ++t) {
    int bbuf = t & 1;
    const char* kbc = kb[bbuf];

    // 1. issue next tile's global loads (held in regs until after phase B)
    f32x4 ld0, ld1, ld2, ld3, ld4, ld5, ld6, ld7;
    if (t < 7) {
      const char* src = kbase + (size_t)(t + 1) * 16 * 4096;
#define LDM(R, M)                                                        \
      {                                                                  \
        int chunk = wv * 8 + (M);                                        \
        int l = chunk >> 2;                                              \
        int c4 = ((chunk)&3) * 1024 + lane * 16;                         \
        R = *reinterpret_cast<const f32x4*>(src + (size_t)l * 4096 +     \
                                            (c4 ^ KSWZ(l)));             \
      }
      LDM(ld0, 0) LDM(ld1, 1) LDM(ld2, 2) LDM(ld3, 3)
      LDM(ld4, 4) LDM(ld5, 5) LDM(ld6, 6) LDM(ld7, 7)
#undef LDM
    }

    // 2. phase A: partial logits, wave covers kc = wv*128 .. +127
    f32x4 acc = {0.f, 0.f, 0.f, 0.f};
#pragma unroll
    for (int mm = 0; mm < 4; ++mm) {
      int kc = wv * 128 + mm * 32 + kg * 8;
      int byte0 = ln16 * 4096 + ((kc * 4) ^ KSWZ(ln16));
      int byte1 = ln16 * 4096 + ((kc * 4 + 16) ^ KSWZ(ln16));
      f32x4 f0 = *reinterpret_cast<const f32x4*>(kbc + byte0);
      f32x4 f1 = *reinterpret_cast<const f32x4*>(kbc + byte1);
      bf16x8 bfr;
      bfr[0] = (bf16)f0[0]; bfr[1] = (bf16)f0[1];
      bfr[2] = (bf16)f0[2]; bfr[3] = (bf16)f0[3];
      bfr[4] = (bf16)f1[0]; bfr[5] = (bf16)f1[1];
      bfr[6] = (bf16)f1[2]; bfr[7] = (bf16)f1[3];
      acc = __builtin_amdgcn_mfma_f32_16x16x32_bf16(afrag[mm], bfr, acc, 0, 0, 0);
    }
    *reinterpret_cast<f32x4*>(&pbuf[wv][ln16][kg * 4]) = acc;
    WAIT_LGKM0;
    SBAR;

    // 3. reduce partials + exp -> sP + attn (unnormalized)
    if (tid < 256) {
      float s = 0.f;
#pragma unroll
      for (int w = 0; w < 8; ++w) s += pbuf[w][rl][rn];
      float p = __expf((s + qbv) * 0.125f);
      sP[rl][rn] = p;
      attn[((size_t)(rn * NB + b)) * NL + sl * 128 + t * 16 + rl] = p;
    }
    WAIT_LGKM0;
    SBAR;

    // 4. phase B: ctxa[n] += p[l][n] * k[l][i]  (f32, conflict-free b128)
#pragma unroll
    for (int j = 0; j < 8; ++j) {
      int l = lh * 8 + j;
      int byte = l * 4096 + ((ic * 16) ^ KSWZ(l));
      f32x4 kf = *reinterpret_cast<const f32x4*>(kbc + byte);
      f32x4 p0 = *reinterpret_cast<const f32x4*>(&sP[l][0]);
      f32x4 p1 = *reinterpret_cast<const f32x4*>(&sP[l][4]);
      f32x4 p2 = *reinterpret_cast<const f32x4*>(&sP[l][8]);
      f32x4 p3 = *reinterpret_cast<const f32x4*>(&sP[l][12]);
#pragma unroll
      for (int n = 0; n < 16; ++n) {
        float pn = (n < 4) ? p0[n]
                 : (n < 8) ? p1[n - 4]
                 : (n < 12) ? p2[n - 8] : p3[n - 12];
        ctxa[n] += pn * kf;
      }
    }

    // 5. stage-write next tile (vmcnt waits happen here, after all compute)
    if (t < 7) {
      char* dst = kb[bbuf ^ 1];
#define STM(R, M)                                                        \
      *reinterpret_cast<f32x4*>(dst + (wv * 8 + (M)) * 1024 + lane * 16) = R;
      STM(ld0, 0) STM(ld1, 1) STM(ld2, 2) STM(ld3, 3)
      STM(ld4, 4) STM(ld5, 5) STM(ld6, 6) STM(ld7, 7)
#undef STM
    }
    WAIT_LGKM0;
    SBAR;
  }

  // epilogue: combine lh pairs via LDS scratch (kb is free now), store slab
  {
    float* sC = (float*)kb;  // [256][17*4] stride-68 floats
    if (lh == 1) {
#pragma unroll
      for (int n = 0; n < 16; ++n)
        *reinterpret_cast<f32x4*>(sC + ic * 68 + n * 4) = ctxa[n];
    }
    WAIT_LGKM0;
    SBAR;
    if (lh == 0) {
#pragma unroll
      for (int n = 0; n < 16; ++n) {
        f32x4 o = *reinterpret_cast<const f32x4*>(sC + ic * 68 + n * 4);
        o += ctxa[n];
        *reinterpret_cast<f32x4*>(
            ctxp + (((size_t)sl * NB + b) * NHH + n) * ND + ic * 4) = o;
      }
    }
  }
}

// ---------------------------------------------------------------------------
// K4: normalize attn rows (divide by row-sum), write invS. grid=512, block=256
// ---------------------------------------------------------------------------
__global__ __launch_bounds__(256) void norm_kernel(float* __restrict__ attn,
                                                   float* __restrict__ invS) {
  int row = blockIdx.x;
  float* p = attn + (size_t)row * NL;
  int tid = threadIdx.x;
  int lane = tid & 63, wv = tid >> 6;
  float v[8];
  float s = 0.f;
#pragma unroll
  for (int j = 0; j < 8; ++j) {
    v[j] = p[tid + j * 256];
    s += v[j];
  }
#pragma unroll
  for (int off = 32; off > 0; off >>= 1) s += __shfl_down(s, off, 64);
  __shared__ float ss[4];
  if (lane == 0) ss[wv] = s;
  __syncthreads();
  float inv = 1.f / (ss[0] + ss[1] + ss[2] + ss[3]);
  if (tid == 0) invS[row] = inv;
#pragma unroll
  for (int j = 0; j < 8; ++j) p[tid + j * 256] = v[j] * inv;
}

// ---------------------------------------------------------------------------
// K5: ctx = sum_sl ctxp[sl]  (unnormalized). grid=512, block=256, f32x4 each
// ---------------------------------------------------------------------------
__global__ __launch_bounds__(256) void reduce_kernel(
    const float* __restrict__ ctxp, float* __restrict__ ctx) {
  size_t e4 = ((size_t)blockIdx.x * 256 + threadIdx.x) * 4;
  f32x4 s = *reinterpret_cast<const f32x4*>(ctxp + e4);
#pragma unroll
  for (int sl = 1; sl < 16; ++sl)
    s += *reinterpret_cast<const f32x4*>(ctxp + (size_t)sl * NB * NHH * ND + e4);
  *reinterpret_cast<f32x4*>(ctx + e4) = s;
}

// ---------------------------------------------------------------------------
// K6: out[b][o] = (Wv[o].ctx[b][n]) * invS[n*32+b] + bv[o]   grid=1024
// ---------------------------------------------------------------------------
__global__ __launch_bounds__(256) void out_kernel(
    const float* __restrict__ Wv, const float* __restrict__ bv,
    const float* __restrict__ ctx, const float* __restrict__ invS,
    float* __restrict__ out) {
  int o = blockIdx.x;
  int n = o >> 6;
  int lane = threadIdx.x & 63;
  int wv = threadIdx.x >> 6;
  const float4* wrow = reinterpret_cast<const float4*>(Wv + (size_t)o * ND) + lane * 4;
  float4 w0 = wrow[0], w1 = wrow[1], w2 = wrow[2], w3 = wrow[3];
#pragma unroll
  for (int bb = 0; bb < 8; ++bb) {
    int b = wv * 8 + bb;
    const float4* cr =
        reinterpret_cast<const float4*>(ctx + ((size_t)(b * NHH + n)) * ND) + lane * 4;
    float s = dot4(cr[0], w0) + dot4(cr[1], w1) + dot4(cr[2], w2) + dot4(cr[3], w3);
#pragma unroll
    for (int off = 32; off > 0; off >>= 1) s += __shfl_down(s, off, 64);
    if (lane == 0) out[(size_t)b * ND + o] = s * invS[n * NB + b] + bv[o];
  }
}

// ---------------------------------------------------------------------------
extern "C" void kernel_launch(void* const* d_in, const int* in_sizes, int n_in,
                              void* d_out, int out_size, void* d_ws, size_t ws_size,
                              hipStream_t stream) {
  const float* q  = (const float*)d_in[0];
  const float* k  = (const float*)d_in[1];
  const float* Wq = (const float*)d_in[2];
  const float* bq = (const float*)d_in[3];
  const float* Wk = (const float*)d_in[4];
  const float* bk = (const float*)d_in[5];
  const float* Wv = (const float*)d_in[6];
  const float* bv = (const float*)d_in[7];

  float* out  = (float*)d_out;         // [32][1024]
  float* attn = out + NB * ND;         // [512][2048]  (n-major)

  // ws floats: qs 32768 | qt 524288 | qb 512 | invS 512 | ctx 524288 |
  //            ctxp 16*524288
  float* ws   = (float*)d_ws;
  float* qs   = ws;
  float* qt   = qs + 32768;
  float* qb   = qt + 524288;
  float* invS = qb + 512;
  float* ctx  = invS + 512;
  float* ctxp = ctx + 524288;

  qs_kernel<<<1024, 256, 0, stream>>>(q, Wq, bq, qs);
  qt_kernel<<<64, 256, 0, stream>>>(Wk, qs, qt);
  qb_kernel<<<2, 256, 0, stream>>>(qs, bk, qb);
  fused_kernel<<<512, 512, 0, stream>>>(k, qt, qb, attn, ctxp);
  norm_kernel<<<512, 256, 0, stream>>>(attn, invS);
  reduce_kernel<<<512, 256, 0, stream>>>(ctxp, ctx);
  out_kernel<<<1024, 256, 0, stream>>>(Wv, bv, ctx, invS, out);
}